// Round 5
// baseline (221.260 us; speedup 1.0000x reference)
//
#include <hip/hip_runtime.h>
#include <cstdint>

#define TDIM 8192   // B_*S_ = 4*2048 flattened tokens
#define MDIM 1024   // in_features (GEMM K)
#define NDIM 1024   // out_features
#define KBITS 8
#define BK 64       // K-depth per staging tile
#define BT 128      // token-rows per block
#define BN 128      // n-cols per block
#define NTILES (MDIM / BK)   // 16

typedef __bf16 bf16x8 __attribute__((ext_vector_type(8)));
typedef float f32x4 __attribute__((ext_vector_type(4)));

#define GAS(p) ((__attribute__((address_space(1))) void*)(uintptr_t)(p))
#define LAS(p) ((__attribute__((address_space(3))) void*)(uintptr_t)(p))

__device__ __forceinline__ unsigned short f2bf(float f) {
    union { float f; unsigned u; } v; v.f = f;
    unsigned r = v.u + 0x7fffu + ((v.u >> 16) & 1u);  // round-to-nearest-even
    return (unsigned short)(r >> 16);
}

// ---- W-fold + counter zeroing (runs before gemm, stream-ordered) ----
// 1024 blocks: Wt[n][m] = bf16( sum_k scale[k][n] * binary[k][m][n] ), 32x32 tiles.
// Block 0 additionally zeroes the 64 per-strip sync counters (the workspace is
// poisoned between iterations, so gemm must never see stale counter values).
__global__ __launch_bounds__(256) void wfold_kernel(const float* __restrict__ binary,
                                                    const float* __restrict__ scale,
                                                    unsigned short* __restrict__ wtr,
                                                    int* __restrict__ cnt) {
    __shared__ float tile[32][33];
    const int tid = threadIdx.x;
    if (blockIdx.x == 0 && tid < 64) cnt[tid] = 0;
    const int n0 = (blockIdx.x & 31) * 32;
    const int m0 = (blockIdx.x >> 5) * 32;
    const int r = tid >> 3;
    const int cn = (tid & 7) * 4;
    f32x4 acc = {0.f, 0.f, 0.f, 0.f};
#pragma unroll
    for (int k = 0; k < KBITS; ++k) {
        f32x4 v = *(const f32x4*)(binary + ((size_t)k * MDIM + m0 + r) * NDIM + n0 + cn);
        f32x4 s = *(const f32x4*)(scale + (size_t)k * NDIM + n0 + cn);
        acc += v * s;
    }
#pragma unroll
    for (int e = 0; e < 4; ++e) tile[cn + e][r] = acc[e];
    __syncthreads();
    const int rn = tid >> 3;
    const int cm = (tid & 7) * 4;
    ushort4 o4;
    o4.x = f2bf(tile[rn][cm + 0]);
    o4.y = f2bf(tile[rn][cm + 1]);
    o4.z = f2bf(tile[rn][cm + 2]);
    o4.w = f2bf(tile[rn][cm + 3]);
    *(ushort4*)(wtr + (size_t)(n0 + rn) * MDIM + m0 + cm) = o4;
}

// ---- gemm with fused A-cast: out[t][n] = sum_m bf16(x[t][m])*Wt[n][m] + bias[n] ----
// The 8 blocks (x, y=0..7) sharing A-strip x cooperatively cast it fp32->bf16 in
// the prologue (16 rows each -- every row cast exactly once chip-wide), signal a
// per-strip device-scope counter (release), spin until all 8 landed (acquire),
// then run the VERIFIED r4 K-loop unchanged (128x128 tile, 4 waves 2Mx2N, BK=64,
// double-buffered global_load_lds, XOR-granule swizzle, 2 blocks/CU).
// This deletes the serial x-cast pass (48MB, ~7.6us) and makes the xb re-read
// L2-hot (producer group == consumer group, same XCD under the %8 mapping).
// Deadlock-safe: grid 512 == 2/CU capacity (64KB LDS) -> all blocks co-resident.
__global__ __launch_bounds__(256, 2) void gemm_kernel(const float* __restrict__ x,
                                                      unsigned short* __restrict__ xb,
                                                      const unsigned short* __restrict__ wtr,
                                                      const float* __restrict__ bias,
                                                      float* __restrict__ out,
                                                      int* __restrict__ cnt) {
    constexpr int ASZ = BT * BK;        // 8192 elems (16 KB)
    constexpr int BSZ = BN * BK;        // 8192 elems (16 KB)
    constexpr int BUF = ASZ + BSZ;      // 16384 elems (32 KB) per buffer
    __shared__ __attribute__((aligned(16))) unsigned short lds[2 * BUF];  // 64 KB

    const int tid = threadIdx.x;
    const int lane = tid & 63;
    const int wv = tid >> 6;        // 0..3
    const int wm = wv >> 1;         // 0..1 (64-row strip)
    const int wn = wv & 1;          // 0..1 (64-col strip)
    const int lrow = lane & 15;
    const int q = lane >> 4;

    const int t0 = blockIdx.x * BT;
    const int n0 = blockIdx.y * BN;

    // ---- fused A-cast: this block casts rows [t0 + y*16, t0 + y*16 + 16) ----
    {
        const int row0 = t0 + blockIdx.y * 16;
#pragma unroll 4
        for (int i = 0; i < 16; ++i) {
            float4 a = *(const float4*)(x + (size_t)(row0 + i) * MDIM + tid * 4);
            ushort4 o;
            o.x = f2bf(a.x); o.y = f2bf(a.y); o.z = f2bf(a.z); o.w = f2bf(a.w);
            *(ushort4*)(xb + (size_t)(row0 + i) * MDIM + tid * 4) = o;
        }
    }
    __syncthreads();   // all casts in this block done
    if (tid == 0)
        __hip_atomic_fetch_add(&cnt[blockIdx.x], 1, __ATOMIC_RELEASE,
                               __HIP_MEMORY_SCOPE_AGENT);
    // spin until all 8 contributors to strip x have signalled (acquire makes
    // their xb writes visible to this block's subsequent reads).
    while (__hip_atomic_load(&cnt[blockIdx.x], __ATOMIC_ACQUIRE,
                             __HIP_MEMORY_SCOPE_AGENT) < 8)
        __builtin_amdgcn_s_sleep(4);
    __syncthreads();

    // ---- verified r4 K-loop below (unchanged) ----
    const unsigned short* srcA[4];
    int dstA[4];
    const unsigned short* srcB[4];
    int dstB[4];
#pragma unroll
    for (int j = 0; j < 4; ++j) {
        int s = tid + j * 256;              // [0, 1024): 128 rows x 8 granules
        int r = s >> 3;
        int g = (s & 7) ^ (r & 7);
        srcA[j] = xb + (size_t)(t0 + r) * MDIM + g * 8;
        dstA[j] = s * 8;
        srcB[j] = wtr + (size_t)(n0 + r) * MDIM + g * 8;
        dstB[j] = ASZ + s * 8;
    }

    // fragment LDS offsets: row m, k-half h, granule (h*4+q)^(m&7)
    int a_off[2][4], b_off[2][4];
#pragma unroll
    for (int h = 0; h < 2; ++h)
#pragma unroll
        for (int i = 0; i < 4; ++i) {
            int m = wm * 64 + i * 16 + lrow;
            a_off[h][i] = (m * 8 + ((h * 4 + q) ^ (m & 7))) * 8;
            int n = wn * 64 + i * 16 + lrow;
            b_off[h][i] = ASZ + (n * 8 + ((h * 4 + q) ^ (n & 7))) * 8;
        }

    f32x4 acc[4][4];
    const f32x4 zero = {0.f, 0.f, 0.f, 0.f};
#pragma unroll
    for (int i = 0; i < 4; ++i)
#pragma unroll
        for (int j = 0; j < 4; ++j) acc[i][j] = zero;

    auto stage = [&](int bufsel, int t) {
        unsigned short* bb = lds + bufsel * BUF;
        const int k0 = t * BK;
#pragma unroll
        for (int j = 0; j < 4; ++j)
            __builtin_amdgcn_global_load_lds(GAS(srcA[j] + k0), LAS(bb + dstA[j]), 16, 0, 0);
#pragma unroll
        for (int j = 0; j < 4; ++j)
            __builtin_amdgcn_global_load_lds(GAS(srcB[j] + k0), LAS(bb + dstB[j]), 16, 0, 0);
    };

    // prologue: stage tile 0, drain, go.
    stage(0, 0);
    __syncthreads();

#pragma unroll
    for (int t = 0; t < NTILES; ++t) {
        const int cur = t & 1;
        // issue tile t+1's staging first: its HBM/L2 latency hides under this
        // tile's ds_reads + MFMAs; the boundary __syncthreads then drains it.
        if (t + 1 < NTILES) stage(cur ^ 1, t + 1);

        const unsigned short* base = lds + cur * BUF;
#pragma unroll
        for (int h = 0; h < 2; ++h) {
            bf16x8 af[4], bfr[4];
#pragma unroll
            for (int i = 0; i < 4; ++i) af[i] = *(const bf16x8*)(base + a_off[h][i]);
#pragma unroll
            for (int i = 0; i < 4; ++i) bfr[i] = *(const bf16x8*)(base + b_off[h][i]);
            __builtin_amdgcn_s_setprio(1);
#pragma unroll
            for (int i = 0; i < 4; ++i)
#pragma unroll
                for (int j = 0; j < 4; ++j)
                    acc[i][j] = __builtin_amdgcn_mfma_f32_16x16x32_bf16(af[i], bfr[j],
                                                                        acc[i][j], 0, 0, 0);
            __builtin_amdgcn_s_setprio(0);
        }

        if (t + 1 < NTILES) __syncthreads();
    }

    // epilogue: C/D layout col=lane&15 (n), row=q*4+reg (t). fuse bias.
#pragma unroll
    for (int j = 0; j < 4; ++j) {
        const int n = n0 + wn * 64 + j * 16 + lrow;
        const float bv = bias[n];
#pragma unroll
        for (int i = 0; i < 4; ++i) {
            const int tb = t0 + wm * 64 + i * 16 + q * 4;
#pragma unroll
            for (int r = 0; r < 4; ++r) {
                out[(size_t)(tb + r) * NDIM + n] = acc[i][j][r] + bv;
            }
        }
    }
}

extern "C" void kernel_launch(void* const* d_in, const int* in_sizes, int n_in,
                              void* d_out, int out_size, void* d_ws, size_t ws_size,
                              hipStream_t stream) {
    const float* x      = (const float*)d_in[0];   // [4,2048,1024] fp32
    const float* binary = (const float*)d_in[1];   // [8,1024,1024] fp32 (+/-1)
    const float* scale  = (const float*)d_in[2];   // [8,1,1024] fp32
    const float* bias   = (const float*)d_in[3];   // [1024] fp32
    float* out = (float*)d_out;                    // [4,2048,1024] fp32

    unsigned short* xb  = (unsigned short*)d_ws;            // 16 MB bf16 x
    unsigned short* wtr = xb + (size_t)TDIM * MDIM;         // 2 MB bf16 Wt[n][m]
    int* cnt = (int*)(wtr + (size_t)NDIM * MDIM);           // 64 per-strip counters

    wfold_kernel<<<1024, 256, 0, stream>>>(binary, scale, wtr, cnt);
    gemm_kernel<<<dim3(TDIM / BT, NDIM / BN), 256, 0, stream>>>(x, xb, wtr, bias, out, cnt);
}

// Round 6
// 131.332 us; speedup vs baseline: 1.6847x; 1.6847x over previous
//
#include <hip/hip_runtime.h>
#include <cstdint>

#define TDIM 8192   // B_*S_ = 4*2048 flattened tokens
#define MDIM 1024   // in_features (GEMM K)
#define NDIM 1024   // out_features
#define KBITS 8
#define BT 128      // token-rows per block
#define BN 128      // n-cols per block

typedef __bf16 bf16x8 __attribute__((ext_vector_type(8)));
typedef float f32x4 __attribute__((ext_vector_type(4)));

__device__ __forceinline__ unsigned f2bf(float f) {
    union { float f; unsigned u; } v; v.f = f;
    unsigned r = v.u + 0x7fffu + ((v.u >> 16) & 1u);  // round-to-nearest-even
    return r >> 16;
}

// ---- packed fragment layout ----
// chunk(tile16, g, ln) = elems [row/col = tile16*16+ln][k = g*8 .. g*8+7], 16B.
// linear short offset = ((tile16*128 + g) * 16 + ln) * 8.
// A wave's MFMA fragment load (ln=lane&15 fast, g=ks*4+q) is then 64 lanes x 16B
// = 1KB CONTIGUOUS -> one global_load_dwordx4 per fragment, perfectly coalesced,
// L2-resident. This removes LDS staging AND all K-loop barriers from the gemm.

// ---- fused prep ----
// blocks [0,1024): W-fold 32x32 tiles -> packed wtrp.
// blocks [1024,1536): x fp32 -> bf16 cast -> packed xbp; block b owns rows
// [16b, 16b+16) (= packed tile b), so every output cache line is completed by
// one block (L2 write-merge friendly). Reads stay row-contiguous/coalesced.
__global__ __launch_bounds__(256) void prep_kernel(const float* __restrict__ x,
                                                   unsigned short* __restrict__ xbp,
                                                   const float* __restrict__ binary,
                                                   const float* __restrict__ scale,
                                                   unsigned short* __restrict__ wtrp) {
    const int tid = threadIdx.x;
    if (blockIdx.x >= 1024) {
        const int b = blockIdx.x - 1024;            // packed tile index (0..511)
        const float* src = x + (size_t)b * 16 * MDIM;
        unsigned short* dst = xbp + (size_t)b * 16384;
#pragma unroll
        for (int p = 0; p < 8; ++p) {
            int s = p * 256 + tid;                  // 0..2047 = 16 rows x 128 granules
            int r16 = s >> 7;                       // row within tile
            int g = s & 127;                        // k-granule
            const float* sp = src + (size_t)r16 * MDIM + g * 8;
            float4 a = *(const float4*)sp;
            float4 c = *(const float4*)(sp + 4);
            uint4 o;
            o.x = f2bf(a.x) | (f2bf(a.y) << 16);
            o.y = f2bf(a.z) | (f2bf(a.w) << 16);
            o.z = f2bf(c.x) | (f2bf(c.y) << 16);
            o.w = f2bf(c.z) | (f2bf(c.w) << 16);
            *(uint4*)(dst + (size_t)g * 128 + r16 * 8) = o;
        }
        return;
    }
    // ---- W-fold: Wt[n][m] = bf16(sum_k scale[k][n]*binary[k][m][n]) ----
    __shared__ float tile[32][33];
    const int n0 = (blockIdx.x & 31) * 32;
    const int m0 = (blockIdx.x >> 5) * 32;
    const int r = tid >> 3;          // m offset 0..31
    const int cn = (tid & 7) * 4;    // n offset 0..28 step 4
    f32x4 acc = {0.f, 0.f, 0.f, 0.f};
#pragma unroll
    for (int k = 0; k < KBITS; ++k) {
        f32x4 v = *(const f32x4*)(binary + ((size_t)k * MDIM + m0 + r) * NDIM + n0 + cn);
        f32x4 s = *(const f32x4*)(scale + (size_t)k * NDIM + n0 + cn);
        acc += v * s;
    }
#pragma unroll
    for (int e = 0; e < 4; ++e) tile[cn + e][r] = acc[e];
    __syncthreads();
    const int rn = tid >> 3;         // n offset 0..31
    const int cm = (tid & 7) * 4;    // m offset 0..28 step 4
    const int n = n0 + rn;
    const int m = m0 + cm;
    ushort4 o4;
    o4.x = (unsigned short)f2bf(tile[rn][cm + 0]);
    o4.y = (unsigned short)f2bf(tile[rn][cm + 1]);
    o4.z = (unsigned short)f2bf(tile[rn][cm + 2]);
    o4.w = (unsigned short)f2bf(tile[rn][cm + 3]);
    // packed write: tile16 = n>>4, ln = n&15, g = m>>3, elem = m&7 (0 or 4)
    *(ushort4*)(wtrp + ((size_t)(n >> 4) * 128 + (m >> 3)) * 128 + (n & 15) * 8 + (m & 7)) = o4;
}

// ---- gemm: out[t][n] = sum_m xb[t][m]*Wt[n][m] + bias[n] ----
// NO LDS, NO BARRIERS: fragments load straight from the packed L2-resident
// buffers. 128x128 tile, 4 waves (2Mx2N, per-wave 64x64), 32 k-steps of
// {4 A-frag loads + 4 B-frag loads + 16 MFMA}. The compiler is free to
// software-pipeline loads across k-steps (nothing to drain, ever); the wn/wm
// wave pairs on the same CU read identical chunks ~simultaneously -> L1 serves
// the duplicate. Per-lane fragment bytes are bit-identical to the verified r4
// kernel, so numerics are unchanged.
// grid (t=64, n=8): 64%8==0 -> linear%8 == x%8: per XCD 8 A-strips (2MB) +
// all of B (2MB) stay L2-resident.
__global__ __launch_bounds__(256, 2) void gemm_kernel(const unsigned short* __restrict__ xbp,
                                                      const unsigned short* __restrict__ wtrp,
                                                      const float* __restrict__ bias,
                                                      float* __restrict__ out) {
    const int tid = threadIdx.x;
    const int lane = tid & 63;
    const int wv = tid >> 6;        // 0..3
    const int wm = wv >> 1;         // 0..1 (64-row strip)
    const int wn = wv & 1;          // 0..1 (64-col strip)
    const int lrow = lane & 15;
    const int q = lane >> 4;

    const int tt0 = blockIdx.x * (BT / 16);   // 8 row-tiles per block
    const int nt0 = blockIdx.y * (BN / 16);   // 8 col-tiles per block

    // fragment base pointers: chunk(tile, g = ks*4 + q, ln = lrow)
    const unsigned short* abase[4];
    const unsigned short* bbase[4];
#pragma unroll
    for (int i = 0; i < 4; ++i) {
        abase[i] = xbp + (size_t)(tt0 + wm * 4 + i) * 16384 + q * 128 + lrow * 8;
        bbase[i] = wtrp + (size_t)(nt0 + wn * 4 + i) * 16384 + q * 128 + lrow * 8;
    }

    f32x4 acc[4][4];
    const f32x4 zero = {0.f, 0.f, 0.f, 0.f};
#pragma unroll
    for (int i = 0; i < 4; ++i)
#pragma unroll
        for (int j = 0; j < 4; ++j) acc[i][j] = zero;

#pragma unroll 4
    for (int ks = 0; ks < 32; ++ks) {
        const int off = ks * 512;            // 4 granules x 128 shorts per k-step
        bf16x8 af[4], bfr[4];
#pragma unroll
        for (int i = 0; i < 4; ++i) af[i] = *(const bf16x8*)(abase[i] + off);
#pragma unroll
        for (int i = 0; i < 4; ++i) bfr[i] = *(const bf16x8*)(bbase[i] + off);
#pragma unroll
        for (int i = 0; i < 4; ++i)
#pragma unroll
            for (int j = 0; j < 4; ++j)
                acc[i][j] = __builtin_amdgcn_mfma_f32_16x16x32_bf16(af[i], bfr[j],
                                                                    acc[i][j], 0, 0, 0);
    }

    // epilogue: C/D layout col=lane&15 (n), row=q*4+reg (t). fuse bias.
    const int t0 = blockIdx.x * BT;
    const int n0 = blockIdx.y * BN;
#pragma unroll
    for (int j = 0; j < 4; ++j) {
        const int n = n0 + wn * 64 + j * 16 + lrow;
        const float bv = bias[n];
#pragma unroll
        for (int i = 0; i < 4; ++i) {
            const int tb = t0 + wm * 64 + i * 16 + q * 4;
#pragma unroll
            for (int r = 0; r < 4; ++r) {
                out[(size_t)(tb + r) * NDIM + n] = acc[i][j][r] + bv;
            }
        }
    }
}

extern "C" void kernel_launch(void* const* d_in, const int* in_sizes, int n_in,
                              void* d_out, int out_size, void* d_ws, size_t ws_size,
                              hipStream_t stream) {
    const float* x      = (const float*)d_in[0];   // [4,2048,1024] fp32
    const float* binary = (const float*)d_in[1];   // [8,1024,1024] fp32 (+/-1)
    const float* scale  = (const float*)d_in[2];   // [8,1,1024] fp32
    const float* bias   = (const float*)d_in[3];   // [1024] fp32
    float* out = (float*)d_out;                    // [4,2048,1024] fp32

    unsigned short* xbp  = (unsigned short*)d_ws;           // 16 MB packed bf16 x
    unsigned short* wtrp = xbp + (size_t)TDIM * MDIM;       // 2 MB packed bf16 Wt

    prep_kernel<<<1024 + TDIM / 16, 256, 0, stream>>>(x, xbp, binary, scale, wtrp);
    gemm_kernel<<<dim3(TDIM / BT, NDIM / BN), 256, 0, stream>>>(xbp, wtrp, bias, out);
}

// Round 7
// 124.714 us; speedup vs baseline: 1.7741x; 1.0531x over previous
//
#include <hip/hip_runtime.h>
#include <cstdint>

#define TDIM 8192   // B_*S_ = 4*2048 flattened tokens
#define MDIM 1024   // in_features (GEMM K)
#define NDIM 1024   // out_features
#define KBITS 8
#define BK 64       // K-depth per A-staging tile
#define BT 128      // token-rows per block
#define BN 128      // n-cols per block
#define NTILES (MDIM / BK)   // 16

typedef __bf16 bf16x8 __attribute__((ext_vector_type(8)));
typedef float f32x4 __attribute__((ext_vector_type(4)));

#define GAS(p) ((__attribute__((address_space(1))) void*)(uintptr_t)(p))
#define LAS(p) ((__attribute__((address_space(3))) void*)(uintptr_t)(p))

__device__ __forceinline__ unsigned f2bf(float f) {
    union { float f; unsigned u; } v; v.f = f;
    unsigned r = v.u + 0x7fffu + ((v.u >> 16) & 1u);  // round-to-nearest-even
    return r >> 16;
}

// ---- fused prep (r4-verified) ----
// blocks [0,1024): W-fold 32x32 tiles -> PACKED wtrp (r6-verified layout):
//   chunk(tile16=n>>4, g=m>>3, ln=n&15) 16B; short off = ((n>>4)*128+(m>>3))*128+(n&15)*8+(m&7)
// blocks [1024,5120): x fp32 -> bf16 cast, LINEAR row-major xb (coalesced 16B/thread).
__global__ __launch_bounds__(256) void prep_kernel(const float* __restrict__ x,
                                                   unsigned short* __restrict__ xb,
                                                   const float* __restrict__ binary,
                                                   const float* __restrict__ scale,
                                                   unsigned short* __restrict__ wtrp) {
    __shared__ float tile[32][33];
    const int tid = threadIdx.x;
    if (blockIdx.x >= 1024) {
        size_t idx = ((size_t)(blockIdx.x - 1024) * 256 + tid) * 8;
        float4 a = *(const float4*)(x + idx);
        float4 b = *(const float4*)(x + idx + 4);
        uint4 o;
        o.x = f2bf(a.x) | (f2bf(a.y) << 16);
        o.y = f2bf(a.z) | (f2bf(a.w) << 16);
        o.z = f2bf(b.x) | (f2bf(b.y) << 16);
        o.w = f2bf(b.z) | (f2bf(b.w) << 16);
        *(uint4*)(xb + idx) = o;
        return;
    }
    const int n0 = (blockIdx.x & 31) * 32;
    const int m0 = (blockIdx.x >> 5) * 32;
    const int r = tid >> 3;          // m offset 0..31
    const int cn = (tid & 7) * 4;    // n offset 0..28 step 4
    f32x4 acc = {0.f, 0.f, 0.f, 0.f};
#pragma unroll
    for (int k = 0; k < KBITS; ++k) {
        f32x4 v = *(const f32x4*)(binary + ((size_t)k * MDIM + m0 + r) * NDIM + n0 + cn);
        f32x4 s = *(const f32x4*)(scale + (size_t)k * NDIM + n0 + cn);
        acc += v * s;
    }
#pragma unroll
    for (int e = 0; e < 4; ++e) tile[cn + e][r] = acc[e];
    __syncthreads();
    const int rn = tid >> 3;         // n offset 0..31
    const int cm = (tid & 7) * 4;    // m offset 0..28 step 4
    const int n = n0 + rn;
    const int m = m0 + cm;
    ushort4 o4;
    o4.x = (unsigned short)f2bf(tile[rn][cm + 0]);
    o4.y = (unsigned short)f2bf(tile[rn][cm + 1]);
    o4.z = (unsigned short)f2bf(tile[rn][cm + 2]);
    o4.w = (unsigned short)f2bf(tile[rn][cm + 3]);
    // packed write (r6-verified): granule g=m>>3, elem m&7 in {0,4}
    *(ushort4*)(wtrp + ((size_t)(n >> 4) * 128 + (m >> 3)) * 128 + (n & 15) * 8 + (m & 7)) = o4;
}

// ---- gemm: out[t][n] = sum_m xb[t][m]*Wt[n][m] + bias[n] ----
// HYBRID: A through the r4-verified LDS path (gload_lds, XOR-granule swizzle,
// double-buffered, 32KB LDS); B fragments load DIRECTLY global->VGPR from the
// packed L2-resident wtrp (r6-verified addressing, bit-identical bytes).
// Rationale: LDS-port traffic (the invariant ~10us floor shared by all four
// schedule variants) halves, B needs no barriers/staging, and 32KB LDS +
// launch_bounds(256,3) lifts occupancy to 3 blocks/CU (12 waves) to cover the
// remaining A barriers. Per tile: B-frag loads issue FIRST, then A(t+1)
// staging -- so the compiler's wait for B is vmcnt(4) (A prefetch stays in
// flight), never a full drain.
// grid (t=64, n=8): 64%8==0 -> linear%8 == x%8: per XCD 8 A-strips (2MB) +
// packed B (2MB) stay L2-resident.
__global__ __launch_bounds__(256, 3) void gemm_kernel(const unsigned short* __restrict__ xb,
                                                      const unsigned short* __restrict__ wtrp,
                                                      const float* __restrict__ bias,
                                                      float* __restrict__ out) {
    constexpr int ASZ = BT * BK;        // 8192 elems (16 KB) per A buffer
    __shared__ __attribute__((aligned(16))) unsigned short lds[2 * ASZ];  // 32 KB

    const int tid = threadIdx.x;
    const int lane = tid & 63;
    const int wv = tid >> 6;        // 0..3
    const int wm = wv >> 1;         // 0..1 (64-row strip)
    const int wn = wv & 1;          // 0..1 (64-col strip)
    const int lrow = lane & 15;
    const int q = lane >> 4;

    const int t0 = blockIdx.x * BT;
    const int n0 = blockIdx.y * BN;
    const int nt0 = blockIdx.y * (BN / 16);   // 8 packed col-tiles per block

    // A staging map (r4-verified): granule (16B) s -> LDS slot s, holding global
    // granule (s&7)^(r&7) of row r = s>>3 (XOR swizzle; bank-conflict-free).
    const unsigned short* srcA[4];
    int dstA[4];
#pragma unroll
    for (int j = 0; j < 4; ++j) {
        int s = tid + j * 256;              // [0, 1024): 128 rows x 8 granules
        int r = s >> 3;
        int g = (s & 7) ^ (r & 7);
        srcA[j] = xb + (size_t)(t0 + r) * MDIM + g * 8;
        dstA[j] = s * 8;
    }

    // A fragment LDS offsets (r4-verified): row m, k-half h, granule (h*4+q)^(m&7)
    int a_off[2][4];
#pragma unroll
    for (int h = 0; h < 2; ++h)
#pragma unroll
        for (int i = 0; i < 4; ++i) {
            int m = wm * 64 + i * 16 + lrow;
            a_off[h][i] = (m * 8 + ((h * 4 + q) ^ (m & 7))) * 8;
        }

    // B fragment base pointers (r6-verified): chunk(tile, g = ks*4 + q, ln = lrow)
    const unsigned short* bbase[4];
#pragma unroll
    for (int i = 0; i < 4; ++i)
        bbase[i] = wtrp + (size_t)(nt0 + wn * 4 + i) * 16384 + q * 128 + lrow * 8;

    f32x4 acc[4][4];
    const f32x4 zero = {0.f, 0.f, 0.f, 0.f};
#pragma unroll
    for (int i = 0; i < 4; ++i)
#pragma unroll
        for (int j = 0; j < 4; ++j) acc[i][j] = zero;

    auto stageA = [&](int bufsel, int t) {
        unsigned short* bb = lds + bufsel * ASZ;
        const int k0 = t * BK;
#pragma unroll
        for (int j = 0; j < 4; ++j)
            __builtin_amdgcn_global_load_lds(GAS(srcA[j] + k0), LAS(bb + dstA[j]), 16, 0, 0);
    };

    // prologue: stage A tile 0, drain, go.
    stageA(0, 0);
    __syncthreads();

#pragma unroll
    for (int t = 0; t < NTILES; ++t) {
        const int cur = t & 1;

        // B fragments for this tile: issue FIRST (so the wait for them keeps
        // the A prefetch below outstanding -> vmcnt(4), not a drain).
        bf16x8 bfr0[4], bfr1[4];
#pragma unroll
        for (int i = 0; i < 4; ++i) bfr0[i] = *(const bf16x8*)(bbase[i] + (t * 2 + 0) * 512);
#pragma unroll
        for (int i = 0; i < 4; ++i) bfr1[i] = *(const bf16x8*)(bbase[i] + (t * 2 + 1) * 512);

        // A staging for t+1: HBM/L2 latency hides under this tile's compute.
        if (t + 1 < NTILES) stageA(cur ^ 1, t + 1);

        const unsigned short* base = lds + cur * ASZ;
#pragma unroll
        for (int h = 0; h < 2; ++h) {
            bf16x8 af[4];
#pragma unroll
            for (int i = 0; i < 4; ++i) af[i] = *(const bf16x8*)(base + a_off[h][i]);
            __builtin_amdgcn_s_setprio(1);
#pragma unroll
            for (int i = 0; i < 4; ++i)
#pragma unroll
                for (int j = 0; j < 4; ++j)
                    acc[i][j] = __builtin_amdgcn_mfma_f32_16x16x32_bf16(
                        af[i], (h == 0) ? bfr0[j] : bfr1[j], acc[i][j], 0, 0, 0);
            __builtin_amdgcn_s_setprio(0);
        }

        if (t + 1 < NTILES) __syncthreads();
    }

    // epilogue (r4-verified): C/D layout col=lane&15 (n), row=q*4+reg (t). fuse bias.
#pragma unroll
    for (int j = 0; j < 4; ++j) {
        const int n = n0 + wn * 64 + j * 16 + lrow;
        const float bv = bias[n];
#pragma unroll
        for (int i = 0; i < 4; ++i) {
            const int tb = t0 + wm * 64 + i * 16 + q * 4;
#pragma unroll
            for (int r = 0; r < 4; ++r) {
                out[(size_t)(tb + r) * NDIM + n] = acc[i][j][r] + bv;
            }
        }
    }
}

extern "C" void kernel_launch(void* const* d_in, const int* in_sizes, int n_in,
                              void* d_out, int out_size, void* d_ws, size_t ws_size,
                              hipStream_t stream) {
    const float* x      = (const float*)d_in[0];   // [4,2048,1024] fp32
    const float* binary = (const float*)d_in[1];   // [8,1024,1024] fp32 (+/-1)
    const float* scale  = (const float*)d_in[2];   // [8,1,1024] fp32
    const float* bias   = (const float*)d_in[3];   // [1024] fp32
    float* out = (float*)d_out;                    // [4,2048,1024] fp32

    unsigned short* xb   = (unsigned short*)d_ws;           // 16 MB bf16 x (linear)
    unsigned short* wtrp = xb + (size_t)TDIM * MDIM;        // 2 MB packed bf16 Wt

    prep_kernel<<<1024 + 4096, 256, 0, stream>>>(x, xb, binary, scale, wtrp);
    gemm_kernel<<<dim3(TDIM / BT, NDIM / BN), 256, 0, stream>>>(xb, wtrp, bias, out);
}